// Round 9
// baseline (1114.472 us; speedup 1.0000x reference)
//
#include <hip/hip_runtime.h>
#include <math.h>

#define B_ 16
#define T_TOT 16
#define C_ 1000
#define N_ 16000          // B_*C_
#define E_ 16000
#define HID 64
#define EMB 32
#define IN_DIM 16
#define IN_CONV 49        // 1 + 1 + 15 + 32
#define HIST 8
#define GRUROWS 180       // 113 (x2) + 3 pad + 64 (hn)
#define XSPLIT 116        // rows <116 feed i_n (x-side); >=116 feed h_n
#define SWTP 36           // swt col pitch (rows+pad, mult of 4, bank-spreading)
#define SXP 180           // sxh row pitch
#define Q_ 16             // scatter partitions

__device__ __forceinline__ float sigmoidf_(float x) { return 1.f / (1.f + expf(-x)); }

// ---------------- init: zero hn, xn, cnt ----------------
__global__ void k_init(float* __restrict__ hn, float* __restrict__ xn, int* __restrict__ cnt) {
  int total = N_ * HID + N_ + C_;
  for (int i = blockIdx.x * 256 + threadIdx.x; i < total; i += gridDim.x * 256) {
    if (i < N_ * HID) hn[i] = 0.f;
    else if (i < N_ * HID + N_) xn[i - N_ * HID] = 0.f;
    else cnt[i - N_ * HID - N_] = 0;
  }
}

// ---------------- prep: transposed GRU weight layout (col-major, pitch 180) ----------------
__global__ void k_prep(const float* __restrict__ W_ih, const float* __restrict__ W_hh,
                       float* __restrict__ WgruT) {
  int i = blockIdx.x * 256 + threadIdx.x;
  if (i < 192 * GRUROWS) {
    int g = i / GRUROWS, j = i - g * GRUROWS;
    float val = 0.f;
    if (j < 113) val = W_ih[g * 113 + j];
    else if (j >= XSPLIT) val = W_hh[g * 64 + (j - XSPLIT)];
    WgruT[i] = val;
  }
}

// ---------------- CSR build: Q_-way parallel deterministic counting scatter ----------------
__global__ __launch_bounds__(256) void k_count(const int* __restrict__ dst,
                                               int* __restrict__ qcnt, int* __restrict__ cnt) {
  const int gw = (blockIdx.x * 256 + threadIdx.x) >> 6;   // C_*Q_ waves
  const int lane = threadIdx.x & 63;
  const int d = gw >> 4, q = gw & (Q_ - 1);
  const int e0 = q * (E_ / Q_);
  int cur = 0;
  for (int base = 0; base < E_ / Q_; base += 64) {
    const bool in = (base + lane) < (E_ / Q_);
    const int e = e0 + (in ? base + lane : 0);
    cur += __popcll(__ballot(in && (dst[e] == d)));
  }
  if (lane == 0) { qcnt[(d << 4) + q] = cur; atomicAdd(&cnt[d], cur); }
}

__global__ __launch_bounds__(1024) void k_scan(const int* __restrict__ cnt, int* __restrict__ rowptr) {
  __shared__ int s[1024];
  int t = threadIdx.x;
  s[t] = (t < C_) ? cnt[t] : 0;
  __syncthreads();
  for (int off = 1; off < 1024; off <<= 1) {
    int v = (t >= off) ? s[t - off] : 0;
    __syncthreads();
    s[t] += v;
    __syncthreads();
  }
  if (t < C_) rowptr[t + 1] = s[t];
  if (t == 0) rowptr[0] = 0;
}

__global__ __launch_bounds__(256) void k_scatter(const int* __restrict__ dst,
                                                 const int* __restrict__ rowptr,
                                                 const int* __restrict__ qcnt,
                                                 int* __restrict__ csr_e) {
  const int gw = (blockIdx.x * 256 + threadIdx.x) >> 6;
  const int lane = threadIdx.x & 63;
  const int d = gw >> 4, q = gw & (Q_ - 1);
  int cur = rowptr[d];
  for (int qq = 0; qq < q; ++qq) cur += qcnt[(d << 4) + qq];
  const int e0 = q * (E_ / Q_);
  for (int base = 0; base < E_ / Q_; base += 64) {
    const bool in = (base + lane) < (E_ / Q_);
    const int e = e0 + (in ? base + lane : 0);
    const bool pred = in && (dst[e] == d);
    const unsigned long long mask = __ballot(pred);
    if (pred) csr_e[cur + __popcll(mask & ((1ull << lane) - 1))] = e;
    cur += __popcll(mask);
  }
}

// ---------------- per-node: build xf, wind, q/k/v/skip, qproj ----------------
__global__ __launch_bounds__(256) void k_node_pre(
    const float* __restrict__ X, const float* __restrict__ y,
    const float* __restrict__ emb_table,
    const float* __restrict__ Wq, const float* __restrict__ bq,
    const float* __restrict__ Wk, const float* __restrict__ bk,
    const float* __restrict__ Wv, const float* __restrict__ bv,
    const float* __restrict__ Wskip, const float* __restrict__ bskip,
    const float* __restrict__ We, const float* __restrict__ be,
    const float* __restrict__ xn_prev,
    float* __restrict__ xf, float* __restrict__ q, float* __restrict__ k,
    float* __restrict__ v, float* __restrict__ skip,
    float* __restrict__ wsp, float* __restrict__ wdir, float* __restrict__ qproj, int t)
{
  __shared__ float sx[4][IN_CONV];
  const int local = threadIdx.x >> 6;
  const int h = threadIdx.x & 63;
  const int n = blockIdx.x * 4 + local;
  const int b = n / C_, c = n % C_;
  const float* Xrow = X + (((b * T_TOT + t) * C_ + c) * IN_DIM);

  if (h == 0)       sx[local][0] = xn_prev[n];
  else if (h == 1)  sx[local][1] = y[(b * T_TOT + t) * C_ + c];
  else if (h <= 16) sx[local][h] = Xrow[h - 2];                    // feats 0..14
  else if (h <= 48) sx[local][h] = emb_table[c * EMB + (h - 17)];  // ids == c
  if (h == 0) {
    float u10 = Xrow[13] * 3.0f + 0.5f;
    float v10 = Xrow[14] * 3.0f - 0.3f;
    float sp = hypotf(u10, v10);
    float dd = 1.5707963267948966f - atan2f(-v10, -u10);
    if (dd <= 0.f) dd += 6.283185307179586f;
    if (sp == 0.f) dd = 0.f;
    wsp[n] = sp; wdir[n] = dd;
  }
  __syncthreads();

  float aq = bq[h], ak = bk[h], av = bv[h], ask = bskip[h];
#pragma unroll
  for (int j = 0; j < IN_CONV; ++j) {
    const float xv = sx[local][j];
    aq  = fmaf(xv, Wq[j * HID + h], aq);
    ak  = fmaf(xv, Wk[j * HID + h], ak);
    av  = fmaf(xv, Wv[j * HID + h], av);
    ask = fmaf(xv, Wskip[j * HID + h], ask);
  }
  q[(size_t)n * HID + h] = aq; k[(size_t)n * HID + h] = ak;
  v[(size_t)n * HID + h] = av; skip[(size_t)n * HID + h] = ask;

  float p0 = aq * be[h];
  float p1 = aq * We[h];
  float p2 = aq * We[64 + h];
  float p3 = aq * We[128 + h];
  float p4 = aq * We[192 + h];
  float p5 = aq * We[256 + h];
#pragma unroll
  for (int off = 1; off < 64; off <<= 1) {
    p0 += __shfl_xor(p0, off); p1 += __shfl_xor(p1, off); p2 += __shfl_xor(p2, off);
    p3 += __shfl_xor(p3, off); p4 += __shfl_xor(p4, off); p5 += __shfl_xor(p5, off);
  }
  if (h < 6) {
    float val = p0;
    if (h == 1) val = p1; else if (h == 2) val = p2; else if (h == 3) val = p3;
    else if (h == 4) val = p4; else if (h == 5) val = p5;
    qproj[(size_t)n * 8 + h] = val;
  }
  if (h < IN_CONV) xf[(size_t)n * IN_CONV + h] = sx[local][h];
}

// ---------------- fused: 16-lane-group CSR attention + 4-node-blocked GRU ----------------
// block = 16 nodes; wave = 4 nodes; grid 1000 = 8*125 XCD swizzle
// GRU weight staging is register-prefetched (wrA/wrB ping-pong): loads for chunk c+1
// issue during compute of chunk c, so the ds_write at c+1 hits arrived data.
__global__ __launch_bounds__(256, 2) void k_node_main(
    const int* __restrict__ src, const int* __restrict__ rowptr, const int* __restrict__ csr_e,
    const float* __restrict__ ea0, const float* __restrict__ We, const float* __restrict__ be,
    const float* __restrict__ q, const float* __restrict__ k, const float* __restrict__ v,
    const float* __restrict__ skip, const float* __restrict__ wsp, const float* __restrict__ wdir,
    const float* __restrict__ xf, const float* __restrict__ qproj,
    const float* __restrict__ WgruT, const float* __restrict__ b_ih, const float* __restrict__ b_hh,
    const float* __restrict__ Wout, const float* __restrict__ bout,
    const float* __restrict__ hn_in, float* __restrict__ hn_out, float* __restrict__ xn_out)
{
  __shared__ float swt[192 * SWTP];      // 27648 B (32-row chunk, col-major)
  __shared__ float sxh[16 * SXP];        // 11520 B (16 nodes x 180 GRU input rows)

  const int h = threadIdx.x & 63;
  const int wv = threadIdx.x >> 6;
  const int grp = h >> 4, t16 = h & 15;
  const int gbase = h & 48;
  const int lb = ((int)blockIdx.x & 7) * 125 + ((int)blockIdx.x >> 3);
  const int nloc = wv * 4 + grp;
  const int n = lb * 16 + nloc;
  const int b = n / C_, d = n % C_;

  const float4 qv4 = *(const float4*)(q + (size_t)n * HID + t16 * 4);
  const float4 pA = *(const float4*)(qproj + (size_t)n * 8);
  const float4 pB = *(const float4*)(qproj + (size_t)n * 8 + 4);

  const int r0 = rowptr[d];
  const int deg = rowptr[d + 1] - r0;

  float m = -INFINITY, s = 0.f, S1 = 0.f, S2 = 0.f, S3 = 0.f, S4 = 0.f, S5 = 0.f;
  float4 o4 = make_float4(0.f, 0.f, 0.f, 0.f);

  for (int cb = 0; cb < deg; cb += 16) {
    const int nb = min(16, deg - cb);
    const int e = csr_e[r0 + cb + (t16 < nb ? t16 : 0)];
    const int nsrc = b * C_ + src[e];
    const int se = src[b * 1000 + (e >> 4)];     // edge_attr0 gathered by src node id
    const float dist = ea0[2 * se], dirc = ea0[2 * se + 1];
    const int sn2 = (e & 15) * C_ + se;
    const float sp = wsp[sn2], wd = wdir[sn2];
    const float adv = fmaxf(0.f, 3.f * sp * cosf(fabsf(dirc - wd)) / dist);
    float asc = pA.x;
    asc = fmaf(dist, pA.y, asc); asc = fmaf(dirc, pA.z, asc); asc = fmaf(sp, pA.w, asc);
    asc = fmaf(wd, pB.x, asc);   asc = fmaf(adv, pB.y, asc);

    float alpha = -INFINITY;
#pragma unroll 4
    for (int j = 0; j < nb; ++j) {
      const int sl = gbase | j;
      const int nsb = __shfl(nsrc, sl);
      const float4 kv = *(const float4*)(k + (size_t)nsb * HID + t16 * 4);
      float part = qv4.x * kv.x + qv4.y * kv.y + qv4.z * kv.z + qv4.w * kv.w;
      part += __shfl_xor(part, 1);
      part += __shfl_xor(part, 2);
      part += __shfl_xor(part, 4);
      part += __shfl_xor(part, 8);
      const float af = (part + __shfl(asc, sl)) * 0.125f;   // 1/sqrt(64)
      if (t16 == j) alpha = af;
    }

    float mx = alpha;
    mx = fmaxf(mx, __shfl_xor(mx, 1));
    mx = fmaxf(mx, __shfl_xor(mx, 2));
    mx = fmaxf(mx, __shfl_xor(mx, 4));
    mx = fmaxf(mx, __shfl_xor(mx, 8));
    const float mnew = fmaxf(m, mx);
    const float scale = expf(m - mnew);
    const float a = expf(alpha - mnew);
    float ra = a, q1 = a * dist, q2 = a * dirc, q3 = a * sp, q4 = a * wd, q5 = a * adv;
#pragma unroll
    for (int off = 1; off < 16; off <<= 1) {
      ra += __shfl_xor(ra, off); q1 += __shfl_xor(q1, off); q2 += __shfl_xor(q2, off);
      q3 += __shfl_xor(q3, off); q4 += __shfl_xor(q4, off); q5 += __shfl_xor(q5, off);
    }
    s  = s * scale + ra;  S1 = S1 * scale + q1; S2 = S2 * scale + q2;
    S3 = S3 * scale + q3; S4 = S4 * scale + q4; S5 = S5 * scale + q5;
    o4.x *= scale; o4.y *= scale; o4.z *= scale; o4.w *= scale;
    m = mnew;

#pragma unroll 4
    for (int j = 0; j < nb; ++j) {
      const int sl = gbase | j;
      const float aj = __shfl(a, sl);
      const int nsb = __shfl(nsrc, sl);
      const float4 v4 = *(const float4*)(v + (size_t)nsb * HID + t16 * 4);
      o4.x = fmaf(aj, v4.x, o4.x); o4.y = fmaf(aj, v4.y, o4.y);
      o4.z = fmaf(aj, v4.z, o4.z); o4.w = fmaf(aj, v4.w, o4.w);
    }
  }

  // reconstruct sum_j a_j*ee_j[h'] and fill GRU input rows
  {
    const float4 be4 = *(const float4*)(be + t16 * 4);
    const float4 e0 = *(const float4*)(We + t16 * 4);
    const float4 e1 = *(const float4*)(We + 64 + t16 * 4);
    const float4 e2 = *(const float4*)(We + 128 + t16 * 4);
    const float4 e3 = *(const float4*)(We + 192 + t16 * 4);
    const float4 e4 = *(const float4*)(We + 256 + t16 * 4);
    const float4 sk4 = *(const float4*)(skip + (size_t)n * HID + t16 * 4);
    const float inv = (s > 0.f) ? 1.f / s : 0.f;
    float* xr = &sxh[nloc * SXP];
    float ox, oy, oz, ow;
    ox = s * be4.x; ox = fmaf(S1, e0.x, ox); ox = fmaf(S2, e1.x, ox); ox = fmaf(S3, e2.x, ox); ox = fmaf(S4, e3.x, ox); ox = fmaf(S5, e4.x, ox);
    oy = s * be4.y; oy = fmaf(S1, e0.y, oy); oy = fmaf(S2, e1.y, oy); oy = fmaf(S3, e2.y, oy); oy = fmaf(S4, e3.y, oy); oy = fmaf(S5, e4.y, oy);
    oz = s * be4.z; oz = fmaf(S1, e0.z, oz); oz = fmaf(S2, e1.z, oz); oz = fmaf(S3, e2.z, oz); oz = fmaf(S4, e3.z, oz); oz = fmaf(S5, e4.z, oz);
    ow = s * be4.w; ow = fmaf(S1, e0.w, ow); ow = fmaf(S2, e1.w, ow); ow = fmaf(S3, e2.w, ow); ow = fmaf(S4, e3.w, ow); ow = fmaf(S5, e4.w, ow);
    xr[49 + t16 * 4 + 0] = sigmoidf_(sk4.x + (o4.x + ox) * inv);
    xr[49 + t16 * 4 + 1] = sigmoidf_(sk4.y + (o4.y + oy) * inv);
    xr[49 + t16 * 4 + 2] = sigmoidf_(sk4.z + (o4.z + oz) * inv);
    xr[49 + t16 * 4 + 3] = sigmoidf_(sk4.w + (o4.w + ow) * inv);
    const float4 hv4 = *(const float4*)(hn_in + (size_t)n * HID + t16 * 4);
    *(float4*)(&xr[XSPLIT + t16 * 4]) = hv4;
    for (int idx = t16; idx < IN_CONV; idx += 16) xr[idx] = xf[(size_t)n * IN_CONV + idx];
    if (t16 < 3) xr[113 + t16] = 0.f;
  }

  // ---- GRU: wave handles 4 nodes; weight staging register-prefetched ----
  float c0[4], c1[4], g2x[4], g2h[4];
  {
    const float bi0 = b_ih[h] + b_hh[h];
    const float bi1 = b_ih[64 + h] + b_hh[64 + h];
    const float bx = b_ih[128 + h], bh = b_hh[128 + h];
#pragma unroll
    for (int i = 0; i < 4; ++i) { c0[i] = bi0; c1[i] = bi1; g2x[i] = bx; g2h[i] = bh; }
  }
  const int nb0 = wv * 4;
  const int su = threadIdx.x;

  float4 wrA[6], wrB[6];
  auto LOADC = [&](float4* r, int base) {
#pragma unroll
    for (int i = 0; i < 6; ++i) {
      const int u = su + i * 256;
      const int g = u >> 3, r4 = (u & 7) * 4;
      if (base + r4 < GRUROWS)
        r[i] = *(const float4*)(WgruT + (size_t)g * GRUROWS + base + r4);
    }
  };
  auto WRITEC = [&](const float4* r, int base) {
#pragma unroll
    for (int i = 0; i < 6; ++i) {
      const int u = su + i * 256;
      const int g = u >> 3, r4 = (u & 7) * 4;
      if (base + r4 < GRUROWS)
        *(float4*)(&swt[g * SWTP + r4]) = r[i];
    }
  };
  auto COMPUTE = [&](int base) {
    const int nrows = min(32, GRUROWS - base);
#pragma unroll 2
    for (int rr = 0; rr < nrows; rr += 4) {
      const bool xs = (base + rr) < XSPLIT;
      const float4 w0 = *(const float4*)(&swt[h * SWTP + rr]);
      const float4 w1 = *(const float4*)(&swt[(64 + h) * SWTP + rr]);
      const float4 w2 = *(const float4*)(&swt[(128 + h) * SWTP + rr]);
#pragma unroll
      for (int i = 0; i < 4; ++i) {
        const float4 xv = *(const float4*)(&sxh[(nb0 + i) * SXP + base + rr]);
        c0[i] = fmaf(xv.x, w0.x, c0[i]); c0[i] = fmaf(xv.y, w0.y, c0[i]);
        c0[i] = fmaf(xv.z, w0.z, c0[i]); c0[i] = fmaf(xv.w, w0.w, c0[i]);
        c1[i] = fmaf(xv.x, w1.x, c1[i]); c1[i] = fmaf(xv.y, w1.y, c1[i]);
        c1[i] = fmaf(xv.z, w1.z, c1[i]); c1[i] = fmaf(xv.w, w1.w, c1[i]);
        const float tg = xv.x * w2.x + xv.y * w2.y + xv.z * w2.z + xv.w * w2.w;
        if (xs) g2x[i] += tg; else g2h[i] += tg;
      }
    }
  };

  LOADC(wrA, 0);
#pragma unroll 1
  for (int c2 = 0; c2 < 3; ++c2) {
    const int b0 = c2 * 64;
    __syncthreads();                       // sxh ready / prev compute done
    WRITEC(wrA, b0);
    if (b0 + 32 < GRUROWS) LOADC(wrB, b0 + 32);   // prefetch under compute(b0)
    __syncthreads();
    COMPUTE(b0);
    __syncthreads();
    WRITEC(wrB, b0 + 32);
    if (b0 + 64 < GRUROWS) LOADC(wrA, b0 + 64);   // prefetch under compute(b0+32)
    __syncthreads();
    COMPUTE(b0 + 32);
  }

  const float wo = Wout[h];
  const float bout0 = bout[0];
#pragma unroll 1
  for (int i = 0; i < 4; ++i) {
    const int ng = lb * 16 + nb0 + i;
    const float hv = sxh[(nb0 + i) * SXP + XSPLIT + h];
    const float rg = sigmoidf_(c0[i]);
    const float zg = sigmoidf_(c1[i]);
    const float nn2 = tanhf(fmaf(rg, g2h[i], g2x[i]));
    const float hnew = (1.f - zg) * nn2 + zg * hv;
    hn_out[(size_t)ng * HID + h] = hnew;
    float prod = hnew * wo;
#pragma unroll
    for (int off = 1; off < 64; off <<= 1) prod += __shfl_xor(prod, off);
    if (h == 0) xn_out[ng] = prod + bout0;
  }
}

extern "C" void kernel_launch(void* const* d_in, const int* in_sizes, int n_in,
                              void* d_out, int out_size, void* d_ws, size_t ws_size,
                              hipStream_t stream) {
  const float* X      = (const float*)d_in[0];
  const float* y      = (const float*)d_in[1];
  const float* ea0    = (const float*)d_in[2];
  const float* emb    = (const float*)d_in[3];
  const float* Wq     = (const float*)d_in[4];
  const float* bq     = (const float*)d_in[5];
  const float* Wk     = (const float*)d_in[6];
  const float* bk     = (const float*)d_in[7];
  const float* Wv     = (const float*)d_in[8];
  const float* bv     = (const float*)d_in[9];
  const float* We     = (const float*)d_in[10];
  const float* be     = (const float*)d_in[11];
  const float* Wskip  = (const float*)d_in[12];
  const float* bskip  = (const float*)d_in[13];
  const float* W_ih   = (const float*)d_in[14];
  const float* b_ih   = (const float*)d_in[15];
  const float* W_hh   = (const float*)d_in[16];
  const float* b_hh   = (const float*)d_in[17];
  const float* Wout   = (const float*)d_in[18];
  const float* bout   = (const float*)d_in[19];
  const int*   eidx   = (const int*)d_in[20];
  const int* src = eidx;
  const int* dst = eidx + E_;

  float* W = (float*)d_ws;
  size_t off = 0;
  float* xf    = W + off; off += (size_t)N_ * IN_CONV;
  float* q     = W + off; off += (size_t)N_ * HID;
  float* k     = W + off; off += (size_t)N_ * HID;
  float* v     = W + off; off += (size_t)N_ * HID;
  float* skip  = W + off; off += (size_t)N_ * HID;
  float* wsp   = W + off; off += N_;
  float* wdr   = W + off; off += N_;
  float* hnA   = W + off; off += (size_t)N_ * HID;
  float* xnA   = W + off; off += N_;
  float* qproj = W + off; off += (size_t)N_ * 8;
  float* WgruT = W + off; off += 192 * GRUROWS + 64;   // +64 pad (guarded tail loads)
  int* cnt     = (int*)(W + off); off += C_;
  int* rowptr  = (int*)(W + off); off += C_ + 1;
  int* qcnt    = (int*)(W + off); off += C_ * Q_;
  int* csr_e   = (int*)(W + off); off += E_;

  k_init<<<1024, 256, 0, stream>>>(hnA, xnA, cnt);
  k_prep<<<(192 * GRUROWS + 255) / 256, 256, 0, stream>>>(W_ih, W_hh, WgruT);
  k_count<<<C_ * Q_ / 4, 256, 0, stream>>>(dst, qcnt, cnt);
  k_scan<<<1, 1024, 0, stream>>>(cnt, rowptr);
  k_scatter<<<C_ * Q_ / 4, 256, 0, stream>>>(dst, rowptr, qcnt, csr_e);

  float* hn_final = (float*)d_out;
  float* xn_final = (float*)d_out + (size_t)N_ * HID;

  for (int t = 0; t < HIST; ++t) {
    const bool last = (t == HIST - 1);
    k_node_pre<<<N_ / 4, 256, 0, stream>>>(X, y, emb, Wq, bq, Wk, bk, Wv, bv, Wskip, bskip,
                                           We, be, xnA, xf, q, k, v, skip, wsp, wdr, qproj, t);
    k_node_main<<<N_ / 16, 256, 0, stream>>>(src, rowptr, csr_e, ea0, We, be,
                                             q, k, v, skip, wsp, wdr, xf, qproj,
                                             WgruT, b_ih, b_hh, Wout, bout,
                                             hnA,
                                             last ? hn_final : hnA,
                                             last ? xn_final : xnA);
  }
}

// Round 10
// 759.517 us; speedup vs baseline: 1.4673x; 1.4673x over previous
//
#include <hip/hip_runtime.h>
#include <math.h>

#define B_ 16
#define T_TOT 16
#define C_ 1000
#define N_ 16000          // B_*C_
#define E_ 16000
#define HID 64
#define EMB 32
#define IN_DIM 16
#define IN_CONV 49        // 1 + 1 + 15 + 32
#define HIST 8
#define GRUROWS 180       // 113 (x2) + 3 pad + 64 (hn)
#define XSPLIT 116        // rows <116 feed i_n (x-side); >=116 feed h_n
#define SWTP 36           // swt col pitch (rows+pad, mult of 4, bank-spreading)
#define SXP 180           // sxh row pitch
#define Q_ 16             // scatter partitions

__device__ __forceinline__ float sigmoidf_(float x) { return 1.f / (1.f + expf(-x)); }

// ---------------- init: zero hn, xn, cnt ----------------
__global__ void k_init(float* __restrict__ hn, float* __restrict__ xn, int* __restrict__ cnt) {
  int total = N_ * HID + N_ + C_;
  for (int i = blockIdx.x * 256 + threadIdx.x; i < total; i += gridDim.x * 256) {
    if (i < N_ * HID) hn[i] = 0.f;
    else if (i < N_ * HID + N_) xn[i - N_ * HID] = 0.f;
    else cnt[i - N_ * HID - N_] = 0;
  }
}

// ---------------- prep: transposed GRU weight layout (col-major, pitch 180) ----------------
__global__ void k_prep(const float* __restrict__ W_ih, const float* __restrict__ W_hh,
                       float* __restrict__ WgruT) {
  int i = blockIdx.x * 256 + threadIdx.x;
  if (i < 192 * GRUROWS) {
    int g = i / GRUROWS, j = i - g * GRUROWS;
    float val = 0.f;
    if (j < 113) val = W_ih[g * 113 + j];
    else if (j >= XSPLIT) val = W_hh[g * 64 + (j - XSPLIT)];
    WgruT[i] = val;
  }
}

// ---------------- CSR build: Q_-way parallel deterministic counting scatter ----------------
__global__ __launch_bounds__(256) void k_count(const int* __restrict__ dst,
                                               int* __restrict__ qcnt, int* __restrict__ cnt) {
  const int gw = (blockIdx.x * 256 + threadIdx.x) >> 6;   // C_*Q_ waves
  const int lane = threadIdx.x & 63;
  const int d = gw >> 4, q = gw & (Q_ - 1);
  const int e0 = q * (E_ / Q_);
  int cur = 0;
  for (int base = 0; base < E_ / Q_; base += 64) {
    const bool in = (base + lane) < (E_ / Q_);
    const int e = e0 + (in ? base + lane : 0);
    cur += __popcll(__ballot(in && (dst[e] == d)));
  }
  if (lane == 0) { qcnt[(d << 4) + q] = cur; atomicAdd(&cnt[d], cur); }
}

__global__ __launch_bounds__(1024) void k_scan(const int* __restrict__ cnt, int* __restrict__ rowptr) {
  __shared__ int s[1024];
  int t = threadIdx.x;
  s[t] = (t < C_) ? cnt[t] : 0;
  __syncthreads();
  for (int off = 1; off < 1024; off <<= 1) {
    int v = (t >= off) ? s[t - off] : 0;
    __syncthreads();
    s[t] += v;
    __syncthreads();
  }
  if (t < C_) rowptr[t + 1] = s[t];
  if (t == 0) rowptr[0] = 0;
}

__global__ __launch_bounds__(256) void k_scatter(const int* __restrict__ dst,
                                                 const int* __restrict__ rowptr,
                                                 const int* __restrict__ qcnt,
                                                 int* __restrict__ csr_e) {
  const int gw = (blockIdx.x * 256 + threadIdx.x) >> 6;
  const int lane = threadIdx.x & 63;
  const int d = gw >> 4, q = gw & (Q_ - 1);
  int cur = rowptr[d];
  for (int qq = 0; qq < q; ++qq) cur += qcnt[(d << 4) + qq];
  const int e0 = q * (E_ / Q_);
  for (int base = 0; base < E_ / Q_; base += 64) {
    const bool in = (base + lane) < (E_ / Q_);
    const int e = e0 + (in ? base + lane : 0);
    const bool pred = in && (dst[e] == d);
    const unsigned long long mask = __ballot(pred);
    if (pred) csr_e[cur + __popcll(mask & ((1ull << lane) - 1))] = e;
    cur += __popcll(mask);
  }
}

// ---------------- pack: CSR-ordered per-(b,edge) record (time-invariant) ----------------
// pack[b*E_+j] = {nsrc, sn2, dist, dirc}: collapses the 3-level gather chain to 1 read
__global__ __launch_bounds__(256) void k_pack(const int* __restrict__ src,
                                              const int* __restrict__ csr_e,
                                              const float* __restrict__ ea0,
                                              int4* __restrict__ pack) {
  const int idx = blockIdx.x * 256 + threadIdx.x;   // 0 .. B_*E_-1
  const int b = idx / E_, j = idx - b * E_;
  const int e = csr_e[j];
  const int se = src[b * 1000 + (e >> 4)];          // edge_attr0 gathered by src node id
  int4 rec;
  rec.x = b * C_ + src[e];                          // nsrc
  rec.y = (e & 15) * C_ + se;                       // sn2 (wind gather index)
  rec.z = __float_as_int(ea0[2 * se]);              // dist
  rec.w = __float_as_int(ea0[2 * se + 1]);          // direc
  pack[idx] = rec;
}

// ---------------- per-node: build xf, wind, q/k/v/skip, qproj ----------------
__global__ __launch_bounds__(256) void k_node_pre(
    const float* __restrict__ X, const float* __restrict__ y,
    const float* __restrict__ emb_table,
    const float* __restrict__ Wq, const float* __restrict__ bq,
    const float* __restrict__ Wk, const float* __restrict__ bk,
    const float* __restrict__ Wv, const float* __restrict__ bv,
    const float* __restrict__ Wskip, const float* __restrict__ bskip,
    const float* __restrict__ We, const float* __restrict__ be,
    const float* __restrict__ xn_prev,
    float* __restrict__ xf, float* __restrict__ q, float* __restrict__ k,
    float* __restrict__ v, float* __restrict__ skip,
    float2* __restrict__ wind, float* __restrict__ qproj, int t)
{
  __shared__ float sx[4][IN_CONV];
  const int local = threadIdx.x >> 6;
  const int h = threadIdx.x & 63;
  const int n = blockIdx.x * 4 + local;
  const int b = n / C_, c = n % C_;
  const float* Xrow = X + (((b * T_TOT + t) * C_ + c) * IN_DIM);

  if (h == 0)       sx[local][0] = xn_prev[n];
  else if (h == 1)  sx[local][1] = y[(b * T_TOT + t) * C_ + c];
  else if (h <= 16) sx[local][h] = Xrow[h - 2];                    // feats 0..14
  else if (h <= 48) sx[local][h] = emb_table[c * EMB + (h - 17)];  // ids == c
  if (h == 0) {
    float u10 = Xrow[13] * 3.0f + 0.5f;
    float v10 = Xrow[14] * 3.0f - 0.3f;
    float sp = hypotf(u10, v10);
    float dd = 1.5707963267948966f - atan2f(-v10, -u10);
    if (dd <= 0.f) dd += 6.283185307179586f;
    if (sp == 0.f) dd = 0.f;
    wind[n] = make_float2(sp, dd);
  }
  __syncthreads();

  float aq = bq[h], ak = bk[h], av = bv[h], ask = bskip[h];
#pragma unroll
  for (int j = 0; j < IN_CONV; ++j) {
    const float xv = sx[local][j];
    aq  = fmaf(xv, Wq[j * HID + h], aq);
    ak  = fmaf(xv, Wk[j * HID + h], ak);
    av  = fmaf(xv, Wv[j * HID + h], av);
    ask = fmaf(xv, Wskip[j * HID + h], ask);
  }
  q[(size_t)n * HID + h] = aq; k[(size_t)n * HID + h] = ak;
  v[(size_t)n * HID + h] = av; skip[(size_t)n * HID + h] = ask;

  float p0 = aq * be[h];
  float p1 = aq * We[h];
  float p2 = aq * We[64 + h];
  float p3 = aq * We[128 + h];
  float p4 = aq * We[192 + h];
  float p5 = aq * We[256 + h];
#pragma unroll
  for (int off = 1; off < 64; off <<= 1) {
    p0 += __shfl_xor(p0, off); p1 += __shfl_xor(p1, off); p2 += __shfl_xor(p2, off);
    p3 += __shfl_xor(p3, off); p4 += __shfl_xor(p4, off); p5 += __shfl_xor(p5, off);
  }
  if (h < 6) {
    float val = p0;
    if (h == 1) val = p1; else if (h == 2) val = p2; else if (h == 3) val = p3;
    else if (h == 4) val = p4; else if (h == 5) val = p5;
    qproj[(size_t)n * 8 + h] = val;
  }
  if (h < IN_CONV) xf[(size_t)n * IN_CONV + h] = sx[local][h];
}

// ---------------- fused: 16-lane-group CSR attention + 4-node-blocked GRU ----------------
// block = 16 nodes; wave = 4 nodes; grid 1000 = 8*125 XCD swizzle
// attention reads the precomputed pack record (1 coalesced int4) + wind float2 gather
__global__ __launch_bounds__(256, 2) void k_node_main(
    const int* __restrict__ rowptr, const int4* __restrict__ pack,
    const float* __restrict__ We, const float* __restrict__ be,
    const float* __restrict__ q, const float* __restrict__ k, const float* __restrict__ v,
    const float* __restrict__ skip, const float2* __restrict__ wind,
    const float* __restrict__ xf, const float* __restrict__ qproj,
    const float* __restrict__ WgruT, const float* __restrict__ b_ih, const float* __restrict__ b_hh,
    const float* __restrict__ Wout, const float* __restrict__ bout,
    const float* __restrict__ hn_in, float* __restrict__ hn_out, float* __restrict__ xn_out)
{
  __shared__ float swt[192 * SWTP];      // 27648 B (32-row chunk, col-major)
  __shared__ float sxh[16 * SXP];        // 11520 B (16 nodes x 180 GRU input rows)

  const int h = threadIdx.x & 63;
  const int wv = threadIdx.x >> 6;
  const int grp = h >> 4, t16 = h & 15;
  const int gbase = h & 48;
  const int lb = ((int)blockIdx.x & 7) * 125 + ((int)blockIdx.x >> 3);
  const int nloc = wv * 4 + grp;
  const int n = lb * 16 + nloc;
  const int b = n / C_, d = n % C_;

  const float4 qv4 = *(const float4*)(q + (size_t)n * HID + t16 * 4);
  const float4 pA = *(const float4*)(qproj + (size_t)n * 8);
  const float4 pB = *(const float4*)(qproj + (size_t)n * 8 + 4);

  const int r0 = rowptr[d];
  const int deg = rowptr[d + 1] - r0;
  const int4* packb = pack + (size_t)b * E_;

  float m = -INFINITY, s = 0.f, S1 = 0.f, S2 = 0.f, S3 = 0.f, S4 = 0.f, S5 = 0.f;
  float4 o4 = make_float4(0.f, 0.f, 0.f, 0.f);

  for (int cb = 0; cb < deg; cb += 16) {
    const int nb = min(16, deg - cb);
    const int4 rec = packb[r0 + cb + (t16 < nb ? t16 : 0)];
    const int nsrc = rec.x;
    const float dist = __int_as_float(rec.z), dirc = __int_as_float(rec.w);
    const float2 w2 = wind[rec.y];
    const float sp = w2.x, wd = w2.y;
    const float adv = fmaxf(0.f, 3.f * sp * cosf(fabsf(dirc - wd)) / dist);
    float asc = pA.x;
    asc = fmaf(dist, pA.y, asc); asc = fmaf(dirc, pA.z, asc); asc = fmaf(sp, pA.w, asc);
    asc = fmaf(wd, pB.x, asc);   asc = fmaf(adv, pB.y, asc);

    float alpha = -INFINITY;
#pragma unroll 4
    for (int j = 0; j < nb; ++j) {
      const int sl = gbase | j;
      const int nsb = __shfl(nsrc, sl);
      const float4 kv = *(const float4*)(k + (size_t)nsb * HID + t16 * 4);
      float part = qv4.x * kv.x + qv4.y * kv.y + qv4.z * kv.z + qv4.w * kv.w;
      part += __shfl_xor(part, 1);
      part += __shfl_xor(part, 2);
      part += __shfl_xor(part, 4);
      part += __shfl_xor(part, 8);
      const float af = (part + __shfl(asc, sl)) * 0.125f;   // 1/sqrt(64)
      if (t16 == j) alpha = af;
    }

    float mx = alpha;
    mx = fmaxf(mx, __shfl_xor(mx, 1));
    mx = fmaxf(mx, __shfl_xor(mx, 2));
    mx = fmaxf(mx, __shfl_xor(mx, 4));
    mx = fmaxf(mx, __shfl_xor(mx, 8));
    const float mnew = fmaxf(m, mx);
    const float scale = expf(m - mnew);
    const float a = expf(alpha - mnew);
    float ra = a, q1 = a * dist, q2 = a * dirc, q3 = a * sp, q4 = a * wd, q5 = a * adv;
#pragma unroll
    for (int off = 1; off < 16; off <<= 1) {
      ra += __shfl_xor(ra, off); q1 += __shfl_xor(q1, off); q2 += __shfl_xor(q2, off);
      q3 += __shfl_xor(q3, off); q4 += __shfl_xor(q4, off); q5 += __shfl_xor(q5, off);
    }
    s  = s * scale + ra;  S1 = S1 * scale + q1; S2 = S2 * scale + q2;
    S3 = S3 * scale + q3; S4 = S4 * scale + q4; S5 = S5 * scale + q5;
    o4.x *= scale; o4.y *= scale; o4.z *= scale; o4.w *= scale;
    m = mnew;

#pragma unroll 4
    for (int j = 0; j < nb; ++j) {
      const int sl = gbase | j;
      const float aj = __shfl(a, sl);
      const int nsb = __shfl(nsrc, sl);
      const float4 v4 = *(const float4*)(v + (size_t)nsb * HID + t16 * 4);
      o4.x = fmaf(aj, v4.x, o4.x); o4.y = fmaf(aj, v4.y, o4.y);
      o4.z = fmaf(aj, v4.z, o4.z); o4.w = fmaf(aj, v4.w, o4.w);
    }
  }

  // reconstruct sum_j a_j*ee_j[h'] and fill GRU input rows
  {
    const float4 be4 = *(const float4*)(be + t16 * 4);
    const float4 e0 = *(const float4*)(We + t16 * 4);
    const float4 e1 = *(const float4*)(We + 64 + t16 * 4);
    const float4 e2 = *(const float4*)(We + 128 + t16 * 4);
    const float4 e3 = *(const float4*)(We + 192 + t16 * 4);
    const float4 e4 = *(const float4*)(We + 256 + t16 * 4);
    const float4 sk4 = *(const float4*)(skip + (size_t)n * HID + t16 * 4);
    const float inv = (s > 0.f) ? 1.f / s : 0.f;
    float* xr = &sxh[nloc * SXP];
    float ox, oy, oz, ow;
    ox = s * be4.x; ox = fmaf(S1, e0.x, ox); ox = fmaf(S2, e1.x, ox); ox = fmaf(S3, e2.x, ox); ox = fmaf(S4, e3.x, ox); ox = fmaf(S5, e4.x, ox);
    oy = s * be4.y; oy = fmaf(S1, e0.y, oy); oy = fmaf(S2, e1.y, oy); oy = fmaf(S3, e2.y, oy); oy = fmaf(S4, e3.y, oy); oy = fmaf(S5, e4.y, oy);
    oz = s * be4.z; oz = fmaf(S1, e0.z, oz); oz = fmaf(S2, e1.z, oz); oz = fmaf(S3, e2.z, oz); oz = fmaf(S4, e3.z, oz); oz = fmaf(S5, e4.z, oz);
    ow = s * be4.w; ow = fmaf(S1, e0.w, ow); ow = fmaf(S2, e1.w, ow); ow = fmaf(S3, e2.w, ow); ow = fmaf(S4, e3.w, ow); ow = fmaf(S5, e4.w, ow);
    xr[49 + t16 * 4 + 0] = sigmoidf_(sk4.x + (o4.x + ox) * inv);
    xr[49 + t16 * 4 + 1] = sigmoidf_(sk4.y + (o4.y + oy) * inv);
    xr[49 + t16 * 4 + 2] = sigmoidf_(sk4.z + (o4.z + oz) * inv);
    xr[49 + t16 * 4 + 3] = sigmoidf_(sk4.w + (o4.w + ow) * inv);
    const float4 hv4 = *(const float4*)(hn_in + (size_t)n * HID + t16 * 4);
    *(float4*)(&xr[XSPLIT + t16 * 4]) = hv4;
    for (int idx = t16; idx < IN_CONV; idx += 16) xr[idx] = xf[(size_t)n * IN_CONV + idx];
    if (t16 < 3) xr[113 + t16] = 0.f;
  }

  // ---- GRU: wave handles 4 nodes (round-7 staging: simple, no reg-prefetch) ----
  float c0[4], c1[4], g2x[4], g2h[4];
  {
    const float bi0 = b_ih[h] + b_hh[h];
    const float bi1 = b_ih[64 + h] + b_hh[64 + h];
    const float bx = b_ih[128 + h], bh = b_hh[128 + h];
#pragma unroll
    for (int i = 0; i < 4; ++i) { c0[i] = bi0; c1[i] = bi1; g2x[i] = bx; g2h[i] = bh; }
  }
  const int nb0 = wv * 4;

#pragma unroll 1
  for (int c = 0; c < 6; ++c) {
    const int base = c * 32;
    const int nrows = min(32, GRUROWS - base);
    __syncthreads();
    for (int u = threadIdx.x; u < 192 * 8; u += 256) {
      const int g = u >> 3, rr = (u & 7) * 4;
      if (base + rr < GRUROWS) {
        const float4 w = *(const float4*)(WgruT + (size_t)g * GRUROWS + base + rr);
        *(float4*)(&swt[g * SWTP + rr]) = w;
      }
    }
    __syncthreads();
#pragma unroll 2
    for (int rr = 0; rr < nrows; rr += 4) {
      const bool xs = (base + rr) < XSPLIT;
      const float4 w0 = *(const float4*)(&swt[h * SWTP + rr]);
      const float4 w1 = *(const float4*)(&swt[(64 + h) * SWTP + rr]);
      const float4 w2 = *(const float4*)(&swt[(128 + h) * SWTP + rr]);
#pragma unroll
      for (int i = 0; i < 4; ++i) {
        const float4 xv = *(const float4*)(&sxh[(nb0 + i) * SXP + base + rr]);
        c0[i] = fmaf(xv.x, w0.x, c0[i]); c0[i] = fmaf(xv.y, w0.y, c0[i]);
        c0[i] = fmaf(xv.z, w0.z, c0[i]); c0[i] = fmaf(xv.w, w0.w, c0[i]);
        c1[i] = fmaf(xv.x, w1.x, c1[i]); c1[i] = fmaf(xv.y, w1.y, c1[i]);
        c1[i] = fmaf(xv.z, w1.z, c1[i]); c1[i] = fmaf(xv.w, w1.w, c1[i]);
        const float tg = xv.x * w2.x + xv.y * w2.y + xv.z * w2.z + xv.w * w2.w;
        if (xs) g2x[i] += tg; else g2h[i] += tg;
      }
    }
  }

  const float wo = Wout[h];
  const float bout0 = bout[0];
#pragma unroll 1
  for (int i = 0; i < 4; ++i) {
    const int ng = lb * 16 + nb0 + i;
    const float hv = sxh[(nb0 + i) * SXP + XSPLIT + h];
    const float rg = sigmoidf_(c0[i]);
    const float zg = sigmoidf_(c1[i]);
    const float nn2 = tanhf(fmaf(rg, g2h[i], g2x[i]));
    const float hnew = (1.f - zg) * nn2 + zg * hv;
    hn_out[(size_t)ng * HID + h] = hnew;
    float prod = hnew * wo;
#pragma unroll
    for (int off = 1; off < 64; off <<= 1) prod += __shfl_xor(prod, off);
    if (h == 0) xn_out[ng] = prod + bout0;
  }
}

extern "C" void kernel_launch(void* const* d_in, const int* in_sizes, int n_in,
                              void* d_out, int out_size, void* d_ws, size_t ws_size,
                              hipStream_t stream) {
  const float* X      = (const float*)d_in[0];
  const float* y      = (const float*)d_in[1];
  const float* ea0    = (const float*)d_in[2];
  const float* emb    = (const float*)d_in[3];
  const float* Wq     = (const float*)d_in[4];
  const float* bq     = (const float*)d_in[5];
  const float* Wk     = (const float*)d_in[6];
  const float* bk     = (const float*)d_in[7];
  const float* Wv     = (const float*)d_in[8];
  const float* bv     = (const float*)d_in[9];
  const float* We     = (const float*)d_in[10];
  const float* be     = (const float*)d_in[11];
  const float* Wskip  = (const float*)d_in[12];
  const float* bskip  = (const float*)d_in[13];
  const float* W_ih   = (const float*)d_in[14];
  const float* b_ih   = (const float*)d_in[15];
  const float* W_hh   = (const float*)d_in[16];
  const float* b_hh   = (const float*)d_in[17];
  const float* Wout   = (const float*)d_in[18];
  const float* bout   = (const float*)d_in[19];
  const int*   eidx   = (const int*)d_in[20];
  const int* src = eidx;
  const int* dst = eidx + E_;

  float* W = (float*)d_ws;
  size_t off = 0;
  float* xf    = W + off; off += (size_t)N_ * IN_CONV;
  float* q     = W + off; off += (size_t)N_ * HID;
  float* k     = W + off; off += (size_t)N_ * HID;
  float* v     = W + off; off += (size_t)N_ * HID;
  float* skip  = W + off; off += (size_t)N_ * HID;
  float2* wind = (float2*)(W + off); off += (size_t)N_ * 2;
  float* hnA   = W + off; off += (size_t)N_ * HID;
  float* xnA   = W + off; off += N_;
  float* qproj = W + off; off += (size_t)N_ * 8;
  float* WgruT = W + off; off += 192 * GRUROWS + 64;
  // 16B-align pack
  off = (off + 3) & ~(size_t)3;
  int4* pack   = (int4*)(W + off); off += (size_t)B_ * E_ * 4;
  int* cnt     = (int*)(W + off); off += C_;
  int* rowptr  = (int*)(W + off); off += C_ + 1;
  int* qcnt    = (int*)(W + off); off += C_ * Q_;
  int* csr_e   = (int*)(W + off); off += E_;

  k_init<<<1024, 256, 0, stream>>>(hnA, xnA, cnt);
  k_prep<<<(192 * GRUROWS + 255) / 256, 256, 0, stream>>>(W_ih, W_hh, WgruT);
  k_count<<<C_ * Q_ / 4, 256, 0, stream>>>(dst, qcnt, cnt);
  k_scan<<<1, 1024, 0, stream>>>(cnt, rowptr);
  k_scatter<<<C_ * Q_ / 4, 256, 0, stream>>>(dst, rowptr, qcnt, csr_e);
  k_pack<<<B_ * E_ / 256, 256, 0, stream>>>(src, csr_e, ea0, pack);

  float* hn_final = (float*)d_out;
  float* xn_final = (float*)d_out + (size_t)N_ * HID;

  for (int t = 0; t < HIST; ++t) {
    const bool last = (t == HIST - 1);
    k_node_pre<<<N_ / 4, 256, 0, stream>>>(X, y, emb, Wq, bq, Wk, bk, Wv, bv, Wskip, bskip,
                                           We, be, xnA, xf, q, k, v, skip, wind, qproj, t);
    k_node_main<<<N_ / 16, 256, 0, stream>>>(rowptr, pack, We, be,
                                             q, k, v, skip, wind, xf, qproj,
                                             WgruT, b_ih, b_hh, Wout, bout,
                                             hnA,
                                             last ? hn_final : hnA,
                                             last ? xn_final : xnA);
  }
}

// Round 11
// 604.036 us; speedup vs baseline: 1.8450x; 1.2574x over previous
//
#include <hip/hip_runtime.h>
#include <math.h>

#define B_ 16
#define T_TOT 16
#define C_ 1000
#define N_ 16000          // B_*C_
#define E_ 16000
#define HID 64
#define EMB 32
#define IN_DIM 16
#define XF 17             // dynamic x rows (xn, y, 15 feats); emb rows folded
#define HIST 8
#define GRUROWS 148       // 17 x-dyn + 64 x_gcn + 3 pad + 64 hn (emb rows folded)
#define XSPLIT 84         // rows <84 feed i_n (x-side); >=84 feed h_n
#define SWTP 36           // swt col pitch (rows+pad, mult of 4, bank-spreading)
#define SXP 148           // sxh row pitch
#define Q_ 16             // scatter partitions

__device__ __forceinline__ float sigmoidf_(float x) { return 1.f / (1.f + expf(-x)); }

// ---------------- init: zero hn, xn, cnt ----------------
__global__ void k_init(float* __restrict__ hn, float* __restrict__ xn, int* __restrict__ cnt) {
  int total = N_ * HID + N_ + C_;
  for (int i = blockIdx.x * 256 + threadIdx.x; i < total; i += gridDim.x * 256) {
    if (i < N_ * HID) hn[i] = 0.f;
    else if (i < N_ * HID + N_) xn[i - N_ * HID] = 0.f;
    else cnt[i - N_ * HID - N_] = 0;
  }
}

// ---------------- prep: folded GRU weight layout (col-major, pitch 148) + WihT2 ----------------
// WgruT[g*148+j]: j<17 -> W_ih[g,j]; 17..80 -> W_ih[g,49+(j-17)]; 81..83 -> 0; 84..147 -> W_hh[g,j-84]
// WihT2[j*192+g] = W_ih[g][17+j]  (emb rows, transposed for coalesced k_embfold reads)
__global__ void k_prep(const float* __restrict__ W_ih, const float* __restrict__ W_hh,
                       float* __restrict__ WgruT, float* __restrict__ WihT2) {
  const int NG = 192 * GRUROWS;
  int i = blockIdx.x * 256 + threadIdx.x;
  if (i < NG) {
    int g = i / GRUROWS, j = i - g * GRUROWS;
    float val = 0.f;
    if (j < 17) val = W_ih[g * 113 + j];
    else if (j < 81) val = W_ih[g * 113 + 49 + (j - 17)];
    else if (j >= 84) val = W_hh[g * 64 + (j - 84)];
    WgruT[i] = val;
  } else if (i < NG + 32 * 192) {
    int i2 = i - NG;
    int j = i2 / 192, g = i2 - j * 192;
    WihT2[i2] = W_ih[g * 113 + 17 + j];
  }
}

// ---------------- embfold (once): fold time-invariant emb rows into per-c bases ----------------
// embW[c][mat*64+h] = sum_j emb[c][j] * Wmat[(17+j)*64+h]   (mat: q,k,v,skip)
// gihemb[c][g]      = sum_j emb[c][j] * W_ih[g][17+j]
__global__ __launch_bounds__(256) void k_embfold(
    const float* __restrict__ emb_table,
    const float* __restrict__ Wq, const float* __restrict__ Wk,
    const float* __restrict__ Wv, const float* __restrict__ Wskip,
    const float* __restrict__ WihT2,
    float* __restrict__ embW, float* __restrict__ gihemb) {
  __shared__ float se[EMB];
  const int c = blockIdx.x;
  const int t = threadIdx.x;
  if (t < EMB) se[t] = emb_table[c * EMB + t];
  __syncthreads();
  const int mat = t >> 6, h = t & 63;
  const float* Wm = (mat == 0) ? Wq : (mat == 1) ? Wk : (mat == 2) ? Wv : Wskip;
  float acc = 0.f;
#pragma unroll
  for (int j = 0; j < EMB; ++j) acc = fmaf(se[j], Wm[(17 + j) * HID + h], acc);
  embW[c * 256 + t] = acc;
  if (t < 192) {
    float a2 = 0.f;
#pragma unroll
    for (int j = 0; j < EMB; ++j) a2 = fmaf(se[j], WihT2[j * 192 + t], a2);
    gihemb[c * 192 + t] = a2;
  }
}

// ---------------- CSR build: Q_-way parallel deterministic counting scatter ----------------
__global__ __launch_bounds__(256) void k_count(const int* __restrict__ dst,
                                               int* __restrict__ qcnt, int* __restrict__ cnt) {
  const int gw = (blockIdx.x * 256 + threadIdx.x) >> 6;   // C_*Q_ waves
  const int lane = threadIdx.x & 63;
  const int d = gw >> 4, q = gw & (Q_ - 1);
  const int e0 = q * (E_ / Q_);
  int cur = 0;
  for (int base = 0; base < E_ / Q_; base += 64) {
    const bool in = (base + lane) < (E_ / Q_);
    const int e = e0 + (in ? base + lane : 0);
    cur += __popcll(__ballot(in && (dst[e] == d)));
  }
  if (lane == 0) { qcnt[(d << 4) + q] = cur; atomicAdd(&cnt[d], cur); }
}

__global__ __launch_bounds__(1024) void k_scan(const int* __restrict__ cnt, int* __restrict__ rowptr) {
  __shared__ int s[1024];
  int t = threadIdx.x;
  s[t] = (t < C_) ? cnt[t] : 0;
  __syncthreads();
  for (int off = 1; off < 1024; off <<= 1) {
    int v = (t >= off) ? s[t - off] : 0;
    __syncthreads();
    s[t] += v;
    __syncthreads();
  }
  if (t < C_) rowptr[t + 1] = s[t];
  if (t == 0) rowptr[0] = 0;
}

__global__ __launch_bounds__(256) void k_scatter(const int* __restrict__ dst,
                                                 const int* __restrict__ rowptr,
                                                 const int* __restrict__ qcnt,
                                                 int* __restrict__ csr_e) {
  const int gw = (blockIdx.x * 256 + threadIdx.x) >> 6;
  const int lane = threadIdx.x & 63;
  const int d = gw >> 4, q = gw & (Q_ - 1);
  int cur = rowptr[d];
  for (int qq = 0; qq < q; ++qq) cur += qcnt[(d << 4) + qq];
  const int e0 = q * (E_ / Q_);
  for (int base = 0; base < E_ / Q_; base += 64) {
    const bool in = (base + lane) < (E_ / Q_);
    const int e = e0 + (in ? base + lane : 0);
    const bool pred = in && (dst[e] == d);
    const unsigned long long mask = __ballot(pred);
    if (pred) csr_e[cur + __popcll(mask & ((1ull << lane) - 1))] = e;
    cur += __popcll(mask);
  }
}

// ---------------- pack: CSR-ordered per-(b,edge) record (time-invariant) ----------------
__global__ __launch_bounds__(256) void k_pack(const int* __restrict__ src,
                                              const int* __restrict__ csr_e,
                                              const float* __restrict__ ea0,
                                              int4* __restrict__ pack) {
  const int idx = blockIdx.x * 256 + threadIdx.x;   // 0 .. B_*E_-1
  const int b = idx / E_, j = idx - b * E_;
  const int e = csr_e[j];
  const int se = src[b * 1000 + (e >> 4)];          // edge_attr0 gathered by src node id
  int4 rec;
  rec.x = b * C_ + src[e];                          // nsrc
  rec.y = (e & 15) * C_ + se;                       // sn2 (wind gather index)
  rec.z = __float_as_int(ea0[2 * se]);              // dist
  rec.w = __float_as_int(ea0[2 * se + 1]);          // direc
  pack[idx] = rec;
}

// ---------------- per-node: build xf (17 dyn rows), wind, q/k/v/skip, qproj ----------------
__global__ __launch_bounds__(256) void k_node_pre(
    const float* __restrict__ X, const float* __restrict__ y,
    const float* __restrict__ embW,
    const float* __restrict__ Wq, const float* __restrict__ bq,
    const float* __restrict__ Wk, const float* __restrict__ bk,
    const float* __restrict__ Wv, const float* __restrict__ bv,
    const float* __restrict__ Wskip, const float* __restrict__ bskip,
    const float* __restrict__ We, const float* __restrict__ be,
    const float* __restrict__ xn_prev,
    float* __restrict__ xf, float* __restrict__ q, float* __restrict__ k,
    float* __restrict__ v, float* __restrict__ skip,
    float2* __restrict__ wind, float* __restrict__ qproj, int t)
{
  __shared__ float sx[4][XF];
  const int local = threadIdx.x >> 6;
  const int h = threadIdx.x & 63;
  const int n = blockIdx.x * 4 + local;
  const int b = n / C_, c = n % C_;
  const float* Xrow = X + (((b * T_TOT + t) * C_ + c) * IN_DIM);

  if (h == 0)       sx[local][0] = xn_prev[n];
  else if (h == 1)  sx[local][1] = y[(b * T_TOT + t) * C_ + c];
  else if (h <= 16) sx[local][h] = Xrow[h - 2];                    // feats 0..14
  if (h == 0) {
    float u10 = Xrow[13] * 3.0f + 0.5f;
    float v10 = Xrow[14] * 3.0f - 0.3f;
    float sp = hypotf(u10, v10);
    float dd = 1.5707963267948966f - atan2f(-v10, -u10);
    if (dd <= 0.f) dd += 6.283185307179586f;
    if (sp == 0.f) dd = 0.f;
    wind[n] = make_float2(sp, dd);
  }
  __syncthreads();

  const float* eW = embW + c * 256;   // folded emb contribution (time-invariant)
  float aq = bq[h] + eW[h];
  float ak = bk[h] + eW[64 + h];
  float av = bv[h] + eW[128 + h];
  float ask = bskip[h] + eW[192 + h];
#pragma unroll
  for (int j = 0; j < XF; ++j) {
    const float xv = sx[local][j];
    aq  = fmaf(xv, Wq[j * HID + h], aq);
    ak  = fmaf(xv, Wk[j * HID + h], ak);
    av  = fmaf(xv, Wv[j * HID + h], av);
    ask = fmaf(xv, Wskip[j * HID + h], ask);
  }
  q[(size_t)n * HID + h] = aq; k[(size_t)n * HID + h] = ak;
  v[(size_t)n * HID + h] = av; skip[(size_t)n * HID + h] = ask;

  float p0 = aq * be[h];
  float p1 = aq * We[h];
  float p2 = aq * We[64 + h];
  float p3 = aq * We[128 + h];
  float p4 = aq * We[192 + h];
  float p5 = aq * We[256 + h];
#pragma unroll
  for (int off = 1; off < 64; off <<= 1) {
    p0 += __shfl_xor(p0, off); p1 += __shfl_xor(p1, off); p2 += __shfl_xor(p2, off);
    p3 += __shfl_xor(p3, off); p4 += __shfl_xor(p4, off); p5 += __shfl_xor(p5, off);
  }
  if (h < 6) {
    float val = p0;
    if (h == 1) val = p1; else if (h == 2) val = p2; else if (h == 3) val = p3;
    else if (h == 4) val = p4; else if (h == 5) val = p5;
    qproj[(size_t)n * 8 + h] = val;
  }
  if (h < XF) xf[(size_t)n * XF + h] = sx[local][h];
}

// ---------------- fused: 16-lane-group CSR attention + 4-node-blocked GRU (148 rows) ----------------
// block = 16 nodes; wave = 4 nodes; grid 1000 = 8*125 XCD swizzle
__global__ __launch_bounds__(256, 2) void k_node_main(
    const int* __restrict__ rowptr, const int4* __restrict__ pack,
    const float* __restrict__ We, const float* __restrict__ be,
    const float* __restrict__ q, const float* __restrict__ k, const float* __restrict__ v,
    const float* __restrict__ skip, const float2* __restrict__ wind,
    const float* __restrict__ xf, const float* __restrict__ qproj,
    const float* __restrict__ WgruT, const float* __restrict__ gihemb,
    const float* __restrict__ b_ih, const float* __restrict__ b_hh,
    const float* __restrict__ Wout, const float* __restrict__ bout,
    const float* __restrict__ hn_in, float* __restrict__ hn_out, float* __restrict__ xn_out)
{
  __shared__ float swt[192 * SWTP];      // 27648 B (32-row chunk, col-major)
  __shared__ float sxh[16 * SXP];        // 9472 B (16 nodes x 148 GRU input rows)

  const int h = threadIdx.x & 63;
  const int wv = threadIdx.x >> 6;
  const int grp = h >> 4, t16 = h & 15;
  const int gbase = h & 48;
  const int lb = ((int)blockIdx.x & 7) * 125 + ((int)blockIdx.x >> 3);
  const int nloc = wv * 4 + grp;
  const int n = lb * 16 + nloc;
  const int b = n / C_, d = n % C_;

  const float4 qv4 = *(const float4*)(q + (size_t)n * HID + t16 * 4);
  const float4 pA = *(const float4*)(qproj + (size_t)n * 8);
  const float4 pB = *(const float4*)(qproj + (size_t)n * 8 + 4);

  const int r0 = rowptr[d];
  const int deg = rowptr[d + 1] - r0;
  const int4* packb = pack + (size_t)b * E_;

  float m = -INFINITY, s = 0.f, S1 = 0.f, S2 = 0.f, S3 = 0.f, S4 = 0.f, S5 = 0.f;
  float4 o4 = make_float4(0.f, 0.f, 0.f, 0.f);

  for (int cb = 0; cb < deg; cb += 16) {
    const int nb = min(16, deg - cb);
    const int4 rec = packb[r0 + cb + (t16 < nb ? t16 : 0)];
    const int nsrc = rec.x;
    const float dist = __int_as_float(rec.z), dirc = __int_as_float(rec.w);
    const float2 w2 = wind[rec.y];
    const float sp = w2.x, wd = w2.y;
    const float adv = fmaxf(0.f, 3.f * sp * cosf(fabsf(dirc - wd)) / dist);
    float asc = pA.x;
    asc = fmaf(dist, pA.y, asc); asc = fmaf(dirc, pA.z, asc); asc = fmaf(sp, pA.w, asc);
    asc = fmaf(wd, pB.x, asc);   asc = fmaf(adv, pB.y, asc);

    float alpha = -INFINITY;
#pragma unroll 4
    for (int j = 0; j < nb; ++j) {
      const int sl = gbase | j;
      const int nsb = __shfl(nsrc, sl);
      const float4 kv = *(const float4*)(k + (size_t)nsb * HID + t16 * 4);
      float part = qv4.x * kv.x + qv4.y * kv.y + qv4.z * kv.z + qv4.w * kv.w;
      part += __shfl_xor(part, 1);
      part += __shfl_xor(part, 2);
      part += __shfl_xor(part, 4);
      part += __shfl_xor(part, 8);
      const float af = (part + __shfl(asc, sl)) * 0.125f;   // 1/sqrt(64)
      if (t16 == j) alpha = af;
    }

    float mx = alpha;
    mx = fmaxf(mx, __shfl_xor(mx, 1));
    mx = fmaxf(mx, __shfl_xor(mx, 2));
    mx = fmaxf(mx, __shfl_xor(mx, 4));
    mx = fmaxf(mx, __shfl_xor(mx, 8));
    const float mnew = fmaxf(m, mx);
    const float scale = expf(m - mnew);
    const float a = expf(alpha - mnew);
    float ra = a, q1 = a * dist, q2 = a * dirc, q3 = a * sp, q4 = a * wd, q5 = a * adv;
#pragma unroll
    for (int off = 1; off < 16; off <<= 1) {
      ra += __shfl_xor(ra, off); q1 += __shfl_xor(q1, off); q2 += __shfl_xor(q2, off);
      q3 += __shfl_xor(q3, off); q4 += __shfl_xor(q4, off); q5 += __shfl_xor(q5, off);
    }
    s  = s * scale + ra;  S1 = S1 * scale + q1; S2 = S2 * scale + q2;
    S3 = S3 * scale + q3; S4 = S4 * scale + q4; S5 = S5 * scale + q5;
    o4.x *= scale; o4.y *= scale; o4.z *= scale; o4.w *= scale;
    m = mnew;

#pragma unroll 4
    for (int j = 0; j < nb; ++j) {
      const int sl = gbase | j;
      const float aj = __shfl(a, sl);
      const int nsb = __shfl(nsrc, sl);
      const float4 v4 = *(const float4*)(v + (size_t)nsb * HID + t16 * 4);
      o4.x = fmaf(aj, v4.x, o4.x); o4.y = fmaf(aj, v4.y, o4.y);
      o4.z = fmaf(aj, v4.z, o4.z); o4.w = fmaf(aj, v4.w, o4.w);
    }
  }

  // reconstruct sum_j a_j*ee_j[h'] and fill GRU input rows
  {
    const float4 be4 = *(const float4*)(be + t16 * 4);
    const float4 e0 = *(const float4*)(We + t16 * 4);
    const float4 e1 = *(const float4*)(We + 64 + t16 * 4);
    const float4 e2 = *(const float4*)(We + 128 + t16 * 4);
    const float4 e3 = *(const float4*)(We + 192 + t16 * 4);
    const float4 e4 = *(const float4*)(We + 256 + t16 * 4);
    const float4 sk4 = *(const float4*)(skip + (size_t)n * HID + t16 * 4);
    const float inv = (s > 0.f) ? 1.f / s : 0.f;
    float* xr = &sxh[nloc * SXP];
    float ox, oy, oz, ow;
    ox = s * be4.x; ox = fmaf(S1, e0.x, ox); ox = fmaf(S2, e1.x, ox); ox = fmaf(S3, e2.x, ox); ox = fmaf(S4, e3.x, ox); ox = fmaf(S5, e4.x, ox);
    oy = s * be4.y; oy = fmaf(S1, e0.y, oy); oy = fmaf(S2, e1.y, oy); oy = fmaf(S3, e2.y, oy); oy = fmaf(S4, e3.y, oy); oy = fmaf(S5, e4.y, oy);
    oz = s * be4.z; oz = fmaf(S1, e0.z, oz); oz = fmaf(S2, e1.z, oz); oz = fmaf(S3, e2.z, oz); oz = fmaf(S4, e3.z, oz); oz = fmaf(S5, e4.z, oz);
    ow = s * be4.w; ow = fmaf(S1, e0.w, ow); ow = fmaf(S2, e1.w, ow); ow = fmaf(S3, e2.w, ow); ow = fmaf(S4, e3.w, ow); ow = fmaf(S5, e4.w, ow);
    xr[17 + t16 * 4 + 0] = sigmoidf_(sk4.x + (o4.x + ox) * inv);   // x_gcn rows 17..80
    xr[17 + t16 * 4 + 1] = sigmoidf_(sk4.y + (o4.y + oy) * inv);
    xr[17 + t16 * 4 + 2] = sigmoidf_(sk4.z + (o4.z + oz) * inv);
    xr[17 + t16 * 4 + 3] = sigmoidf_(sk4.w + (o4.w + ow) * inv);
    const float4 hv4 = *(const float4*)(hn_in + (size_t)n * HID + t16 * 4);
    *(float4*)(&xr[XSPLIT + t16 * 4]) = hv4;                       // hn rows 84..147
    for (int idx = t16; idx < XF; idx += 16) xr[idx] = xf[(size_t)n * XF + idx];
    if (t16 < 3) xr[81 + t16] = 0.f;                               // pad rows
  }

  // ---- GRU: wave handles 4 nodes; 148 rows; gihemb folded into accumulator init ----
  float c0[4], c1[4], g2x[4], g2h[4];
  {
    const float bi0 = b_ih[h] + b_hh[h];
    const float bi1 = b_ih[64 + h] + b_hh[64 + h];
    const float bx = b_ih[128 + h], bh2 = b_hh[128 + h];
#pragma unroll
    for (int i = 0; i < 4; ++i) {
      const int ci = (lb * 16 + (wv * 4) + i) % C_;
      const float* ge = gihemb + (size_t)ci * 192;
      c0[i] = bi0 + ge[h];
      c1[i] = bi1 + ge[64 + h];
      g2x[i] = bx + ge[128 + h];     // emb rows are x-side
      g2h[i] = bh2;
    }
  }
  const int nb0 = wv * 4;

#pragma unroll 1
  for (int c = 0; c < 5; ++c) {
    const int base = c * 32;
    const int nrows = min(32, GRUROWS - base);
    __syncthreads();
    for (int u = threadIdx.x; u < 192 * 8; u += 256) {
      const int g = u >> 3, rr = (u & 7) * 4;
      if (base + rr < GRUROWS) {
        const float4 w = *(const float4*)(WgruT + (size_t)g * GRUROWS + base + rr);
        *(float4*)(&swt[g * SWTP + rr]) = w;
      }
    }
    __syncthreads();
#pragma unroll 2
    for (int rr = 0; rr < nrows; rr += 4) {
      const bool xs = (base + rr) < XSPLIT;
      const float4 w0 = *(const float4*)(&swt[h * SWTP + rr]);
      const float4 w1 = *(const float4*)(&swt[(64 + h) * SWTP + rr]);
      const float4 w2 = *(const float4*)(&swt[(128 + h) * SWTP + rr]);
#pragma unroll
      for (int i = 0; i < 4; ++i) {
        const float4 xv = *(const float4*)(&sxh[(nb0 + i) * SXP + base + rr]);
        c0[i] = fmaf(xv.x, w0.x, c0[i]); c0[i] = fmaf(xv.y, w0.y, c0[i]);
        c0[i] = fmaf(xv.z, w0.z, c0[i]); c0[i] = fmaf(xv.w, w0.w, c0[i]);
        c1[i] = fmaf(xv.x, w1.x, c1[i]); c1[i] = fmaf(xv.y, w1.y, c1[i]);
        c1[i] = fmaf(xv.z, w1.z, c1[i]); c1[i] = fmaf(xv.w, w1.w, c1[i]);
        const float tg = xv.x * w2.x + xv.y * w2.y + xv.z * w2.z + xv.w * w2.w;
        if (xs) g2x[i] += tg; else g2h[i] += tg;
      }
    }
  }

  const float wo = Wout[h];
  const float bout0 = bout[0];
#pragma unroll 1
  for (int i = 0; i < 4; ++i) {
    const int ng = lb * 16 + nb0 + i;
    const float hv = sxh[(nb0 + i) * SXP + XSPLIT + h];
    const float rg = sigmoidf_(c0[i]);
    const float zg = sigmoidf_(c1[i]);
    const float nn2 = tanhf(fmaf(rg, g2h[i], g2x[i]));
    const float hnew = (1.f - zg) * nn2 + zg * hv;
    hn_out[(size_t)ng * HID + h] = hnew;
    float prod = hnew * wo;
#pragma unroll
    for (int off = 1; off < 64; off <<= 1) prod += __shfl_xor(prod, off);
    if (h == 0) xn_out[ng] = prod + bout0;
  }
}

extern "C" void kernel_launch(void* const* d_in, const int* in_sizes, int n_in,
                              void* d_out, int out_size, void* d_ws, size_t ws_size,
                              hipStream_t stream) {
  const float* X      = (const float*)d_in[0];
  const float* y      = (const float*)d_in[1];
  const float* ea0    = (const float*)d_in[2];
  const float* emb    = (const float*)d_in[3];
  const float* Wq     = (const float*)d_in[4];
  const float* bq     = (const float*)d_in[5];
  const float* Wk     = (const float*)d_in[6];
  const float* bk     = (const float*)d_in[7];
  const float* Wv     = (const float*)d_in[8];
  const float* bv     = (const float*)d_in[9];
  const float* We     = (const float*)d_in[10];
  const float* be     = (const float*)d_in[11];
  const float* Wskip  = (const float*)d_in[12];
  const float* bskip  = (const float*)d_in[13];
  const float* W_ih   = (const float*)d_in[14];
  const float* b_ih   = (const float*)d_in[15];
  const float* W_hh   = (const float*)d_in[16];
  const float* b_hh   = (const float*)d_in[17];
  const float* Wout   = (const float*)d_in[18];
  const float* bout   = (const float*)d_in[19];
  const int*   eidx   = (const int*)d_in[20];
  const int* src = eidx;
  const int* dst = eidx + E_;

  float* W = (float*)d_ws;
  size_t off = 0;
  float* xf    = W + off; off += (size_t)N_ * XF;
  float* q     = W + off; off += (size_t)N_ * HID;
  float* k     = W + off; off += (size_t)N_ * HID;
  float* v     = W + off; off += (size_t)N_ * HID;
  float* skip  = W + off; off += (size_t)N_ * HID;
  float2* wind = (float2*)(W + off); off += (size_t)N_ * 2;
  float* hnA   = W + off; off += (size_t)N_ * HID;
  float* xnA   = W + off; off += N_;
  float* qproj = W + off; off += (size_t)N_ * 8;
  float* WgruT = W + off; off += 192 * GRUROWS + 64;
  float* WihT2 = W + off; off += 32 * 192;
  float* embW  = W + off; off += (size_t)C_ * 256;
  float* gihemb= W + off; off += (size_t)C_ * 192;
  // 16B-align pack
  off = (off + 3) & ~(size_t)3;
  int4* pack   = (int4*)(W + off); off += (size_t)B_ * E_ * 4;
  int* cnt     = (int*)(W + off); off += C_;
  int* rowptr  = (int*)(W + off); off += C_ + 1;
  int* qcnt    = (int*)(W + off); off += C_ * Q_;
  int* csr_e   = (int*)(W + off); off += E_;

  k_init<<<1024, 256, 0, stream>>>(hnA, xnA, cnt);
  k_prep<<<(192 * GRUROWS + 32 * 192 + 255) / 256, 256, 0, stream>>>(W_ih, W_hh, WgruT, WihT2);
  k_embfold<<<C_, 256, 0, stream>>>(emb, Wq, Wk, Wv, Wskip, WihT2, embW, gihemb);
  k_count<<<C_ * Q_ / 4, 256, 0, stream>>>(dst, qcnt, cnt);
  k_scan<<<1, 1024, 0, stream>>>(cnt, rowptr);
  k_scatter<<<C_ * Q_ / 4, 256, 0, stream>>>(dst, rowptr, qcnt, csr_e);
  k_pack<<<B_ * E_ / 256, 256, 0, stream>>>(src, csr_e, ea0, pack);

  float* hn_final = (float*)d_out;
  float* xn_final = (float*)d_out + (size_t)N_ * HID;

  for (int t = 0; t < HIST; ++t) {
    const bool last = (t == HIST - 1);
    k_node_pre<<<N_ / 4, 256, 0, stream>>>(X, y, embW, Wq, bq, Wk, bk, Wv, bv, Wskip, bskip,
                                           We, be, xnA, xf, q, k, v, skip, wind, qproj, t);
    k_node_main<<<N_ / 16, 256, 0, stream>>>(rowptr, pack, We, be,
                                             q, k, v, skip, wind, xf, qproj,
                                             WgruT, gihemb, b_ih, b_hh, Wout, bout,
                                             hnA,
                                             last ? hn_final : hnA,
                                             last ? xn_final : xnA);
  }
}